// Round 11
// baseline (757.660 us; speedup 1.0000x reference)
//
#include <hip/hip_runtime.h>

typedef _Float16 f16x8 __attribute__((ext_vector_type(8)));
typedef float f32x4 __attribute__((ext_vector_type(4)));

#define EPS 1e-5f

__device__ __forceinline__ short f2h(float x) {
    _Float16 h = (_Float16)x;   // round-to-nearest-even v_cvt_f16_f32
    union { _Float16 h; short s; } u;
    u.h = h;
    return u.s;
}

// ---------------------------------------------------------------------------
// prep: transpose+convert Wm -> WtM[l][f][k] fp16, Wl -> WtF[f][k] fp16 (f padded
// to 48 with zeros), zero the stats buffers. Runs every call (ws is re-poisoned).
// ---------------------------------------------------------------------------
__global__ void prep_kernel(const float* __restrict__ Wm, const float* __restrict__ Wl,
                            short* __restrict__ WtM, short* __restrict__ WtF,
                            float* __restrict__ stats) {
    const long T1 = 14L * 896 * 128;
    const long T2 = 48L * 896;
    const long T3 = 15L * 256;
    long i = (long)blockIdx.x * blockDim.x + threadIdx.x;
    if (i < T1) {
        long l = i / (896 * 128);
        long r = i % (896 * 128);
        long k = r >> 7;
        long f = r & 127;
        WtM[l * 114688 + f * 896 + k] = f2h(Wm[i]);
    } else if (i < T1 + T2) {
        long j = i - T1;
        long f = j / 896;
        long k = j % 896;
        WtF[j] = (f < 36) ? f2h(Wl[k * 36 + f]) : (short)0;
    } else if (i < T1 + T2 + T3) {
        stats[i - T1 - T2] = 0.0f;
    }
}

// ---------------------------------------------------------------------------
// layer0: h[n,f] = b0[f] + sum_{k<21} x[idx[n,k/3], k%3] * W0[k,f]
// W in 21 registers; grid-stride (1280 blocks) with depth-1 register prefetch
// of the gathered x staging. fp32 math; fp16 output + exact fp32 stats.
// (R8 version verbatim.)
// ---------------------------------------------------------------------------
#define L0_NB 16
__global__ __launch_bounds__(256) void layer0_kernel(
        const float* __restrict__ x, const int* __restrict__ idx,
        const float* __restrict__ W0, const float* __restrict__ b0,
        short* __restrict__ hlin, float* __restrict__ stats, int N) {
    __shared__ float sX[L0_NB * 21];
    __shared__ float sStat[256];
    const int tid = threadIdx.x;
    const int f = tid & 127;
    const int half = tid >> 7;
    float wreg[21];
#pragma unroll
    for (int k = 0; k < 21; ++k) wreg[k] = W0[k * 128 + f];
    const float bf = b0[f];
    float s = 0.f, ss = 0.f;
    const int ntiles = (N + L0_NB - 1) / L0_NB;
    const int gs = gridDim.x;

    const int e0 = tid;                 // always < 336
    const int ni0 = e0 / 21, k0e = e0 - ni0 * 21;
    const int j0 = k0e / 3, c0 = k0e - j0 * 3;
    const int e1 = tid + 256;           // valid only for tid < 80
    const int ni1 = e1 / 21, k1e = e1 - ni1 * 21;
    const int j1 = k1e / 3, c1 = k1e - j1 * 3;

    auto issueX = [&](int t, float& a0, float& a1) {
        if (t >= ntiles) return;
        const int base = t * L0_NB;
        int n = base + ni0; if (n >= N) n = N - 1;
        a0 = x[(long)idx[n * 7 + j0] * 3 + c0];
        if (tid < 80) {
            int n2 = base + ni1; if (n2 >= N) n2 = N - 1;
            a1 = x[(long)idx[n2 * 7 + j1] * 3 + c1];
        }
    };

    float cx0 = 0.f, cx1 = 0.f, nx0 = 0.f, nx1 = 0.f;
    issueX(blockIdx.x, cx0, cx1);

    for (int t = blockIdx.x; t < ntiles; t += gs) {
        const int n0 = t * L0_NB;
        __syncthreads();                 // sX free (previous compute done)
        sX[e0] = cx0;                    // consume prefetch (vmcnt waits here)
        if (tid < 80) sX[e1] = cx1;
        issueX(t + gs, nx0, nx1);        // issue next tile BEFORE compute
        __syncthreads();
#pragma unroll
        for (int ni = 0; ni < 8; ++ni) {
            int node = n0 + half * 8 + ni;
            if (node >= N) break;        // per-thread, no barrier inside
            float acc = bf;
#pragma unroll
            for (int k = 0; k < 21; ++k)
                acc = fmaf(sX[(half * 8 + ni) * 21 + k], wreg[k], acc);
            hlin[(long)node * 128 + f] = f2h(acc);
            s += acc;
            ss += acc * acc;
        }
        cx0 = nx0; cx1 = nx1;            // plain register moves (no dyn index)
    }
    __syncthreads();
    if (half == 1) { sStat[f] = s; sStat[128 + f] = ss; }
    __syncthreads();
    if (half == 0) {
        atomicAdd(&stats[f], s + sStat[f]);
        atomicAdd(&stats[128 + f], ss + sStat[128 + f]);
    }
}

// ---------------------------------------------------------------------------
// gemm_mid (BN-fused, software-pipelined, 32 nodes x 64 feats, XCD-pair swz):
//   Concurrency-first geometry: LDS = sA(8.7K)+sB(17.4K)+sAux(1K) = 27,136B
//   -> 5 blocks/CU (launch_bounds(256,5), VGPR cap 102) = 20 waves/CU (was 16).
//   2562 units on 1280 slots = exactly 2 rounds of a ~0.65x-sized unit.
//   Pipeline identical to the proven R8/R10 shape: depth-1 register prefetch
//   of A+B issued before the MFMA phase; fp16 gather -> fp32 BN+ReLU -> f16 sA.
//   XCD-pair swizzle kept: fg pair of a tile shares 57KB of gathered rows on
//   one XCD's L2. bx: tile=((bx>>4)<<3)|(bx&7), fg=(bx>>3)&1.
// Block: 256 thr = 4 waves; wave = 16 nodes (wm) x 32 feats (wf); acc[2] f32x4.
// ---------------------------------------------------------------------------
__global__ __launch_bounds__(256, 5) void gemm_mid_kernel(
        const short* __restrict__ hprev, const int* __restrict__ idx,
        const short* __restrict__ Wt, const float* __restrict__ bvec,
        const float* __restrict__ g, const float* __restrict__ be,
        const float* __restrict__ statsIn,
        short* __restrict__ hlin, float* __restrict__ statsOut,
        int N, float invN) {
    __shared__ short sA[32 * 136];   // [node][k] for current j
    __shared__ short sB[64 * 136];   // [feat_local][k] for current j
    __shared__ float sAux[256];      // sc|sh during staging; stats scratch later

    const int bx = blockIdx.x;
    const int tile = ((bx >> 4) << 3) | (bx & 7);
    const int fg = (bx >> 3) & 1;   // feature group: feats [fg*64, fg*64+64)
    const int nT = (N + 31) >> 5;
    if (tile >= nT) return;          // pad blocks exit before any barrier

    const int tid = threadIdx.x;
    const int wave = tid >> 6;
    const int lane = tid & 63;
    const int quad = lane >> 4;
    const int l16 = lane & 15;
    const int wm = wave & 1;        // node half (16 nodes)
    const int wf = wave >> 1;       // feat half of the 64 (32 feats)
    const int m0 = tile * 32;
    const int f0 = fg * 64;
    const int t16 = tid >> 4;       // 0..15: staging row group
    const int fb = (tid & 15) * 8;  // fixed k-chunk for staging (input feats)

    if (tid < 128) {
        float mu = statsIn[tid] * invN;
        float var = statsIn[128 + tid] * invN - mu * mu;
        float rs = rsqrtf(var + EPS);
        float sc = g[tid] * rs;
        sAux[tid] = sc;
        sAux[128 + tid] = be[tid] - mu * sc;
    }
    __syncthreads();
    float scR[8], shR[8];
#pragma unroll
    for (int e = 0; e < 8; ++e) {
        scR[e] = sAux[fb + e];
        shR[e] = sAux[128 + fb + e];
    }

    f32x4 acc[2];
#pragma unroll
    for (int ni = 0; ni < 2; ++ni) {
        float bv0 = bvec[f0 + wf * 32 + ni * 16 + l16];
        acc[ni][0] = bv0; acc[ni][1] = bv0; acc[ni][2] = bv0; acc[ni][3] = bv0;
    }

    f16x8 av[2];    // A prefetch: 2 gathered fp16 row-chunks
    f16x8 bv[4];    // B prefetch: 4 chunks of 8 fp16

    auto issueA = [&](int j) {
#pragma unroll
        for (int it = 0; it < 2; ++it) {
            int nl = t16 + it * 16;
            int n = m0 + nl;
            n = (n < N) ? n : (N - 1);
            long row = idx[n * 7 + j];
            av[it] = *(const f16x8*)&hprev[row * 128 + fb];
        }
    };
    auto issueB = [&](int j) {
#pragma unroll
        for (int it = 0; it < 4; ++it) {
            int ff = f0 + t16 + it * 16;
            bv[it] = *(const f16x8*)&Wt[(long)ff * 896 + j * 128 + fb];
        }
    };
    auto writeA = [&]() {
#pragma unroll
        for (int it = 0; it < 2; ++it) {
            int nl = t16 + it * 16;
            f16x8 hv = av[it];
            union { short sh8[8]; f16x8 v; } u;
#pragma unroll
            for (int e = 0; e < 8; ++e) {
                float v = (float)hv[e];
                u.sh8[e] = f2h(fmaxf(fmaf(v, scR[e], shR[e]), 0.f));
            }
            *(f16x8*)&sA[nl * 136 + fb] = u.v;
        }
    };
    auto writeB = [&]() {
#pragma unroll
        for (int it = 0; it < 4; ++it) {
            int ffl = t16 + it * 16;
            *(f16x8*)&sB[ffl * 136 + fb] = bv[it];
        }
    };

    issueB(0);
    issueA(0);

    for (int j = 0; j < 7; ++j) {
        __syncthreads();            // sA/sB free (previous MFMA done)
        writeB();                   // implicit vmcnt waits at first use
        writeA();
        if (j < 6) {                // issue j+1 BEFORE compute of j
            issueB(j + 1);
            issueA(j + 1);
        }
        __syncthreads();
#pragma unroll
        for (int k0 = 0; k0 < 128; k0 += 32) {
            f16x8 a = *(const f16x8*)&sA[(wm * 16 + l16) * 136 + k0 + quad * 8];
            f16x8 b[2];
#pragma unroll
            for (int ni = 0; ni < 2; ++ni)
                b[ni] = *(const f16x8*)&sB[(wf * 32 + ni * 16 + l16) * 136 + k0 + quad * 8];
#pragma unroll
            for (int ni = 0; ni < 2; ++ni)
                acc[ni] = __builtin_amdgcn_mfma_f32_16x16x32_f16(a, b[ni], acc[ni], 0, 0, 0);
        }
    }

    // epilogue: store h fp16 (pre-BN), accumulate per-feature fp32 stats
    __syncthreads();
    if (tid < 128) sAux[tid] = 0.f;
    __syncthreads();
#pragma unroll
    for (int ni = 0; ni < 2; ++ni) {
        int lf = wf * 32 + ni * 16 + l16;     // local feat 0..63
        float s = 0.f, ss = 0.f;
#pragma unroll
        for (int r = 0; r < 4; ++r) {
            int node = m0 + wm * 16 + quad * 4 + r;
            float v = acc[ni][r];
            if (node < N) {
                hlin[(long)node * 128 + f0 + lf] = f2h(v);
                s += v;
                ss += v * v;
            }
        }
        atomicAdd(&sAux[lf], s);
        atomicAdd(&sAux[64 + lf], ss);
    }
    __syncthreads();
    if (tid < 64) {
        atomicAdd(&statsOut[f0 + tid], sAux[tid]);
        atomicAdd(&statsOut[128 + f0 + tid], sAux[64 + tid]);
    }
}

// ---------------------------------------------------------------------------
// gemm_final (BN-fused, software-pipelined, fp16 h gather — R8 verbatim):
//   out[N,36] = gather7(relu(bn(hprev)))[N,896] @ Wl + bl
// WtF: [48][896] fp16 (feats 36..47 zero). Block: 64 nodes, wave = 16 nodes x 48 feats.
// ---------------------------------------------------------------------------
__global__ __launch_bounds__(256) void gemm_final_kernel(
        const short* __restrict__ hprev, const int* __restrict__ idx,
        const short* __restrict__ WtF, const float* __restrict__ bl,
        const float* __restrict__ g, const float* __restrict__ be,
        const float* __restrict__ statsIn,
        float* __restrict__ out, int N, float invN) {
    __shared__ short sA[64 * 136];
    __shared__ short sB[48 * 136];
    __shared__ float sAux[256];

    const int tid = threadIdx.x;
    const int wave = tid >> 6;
    const int lane = tid & 63;
    const int quad = lane >> 4;
    const int l16 = lane & 15;
    const int m0 = blockIdx.x * 64;
    const int t16 = tid >> 4;
    const int fb = (tid & 15) * 8;

    if (tid < 128) {
        float mu = statsIn[tid] * invN;
        float var = statsIn[128 + tid] * invN - mu * mu;
        float rs = rsqrtf(var + EPS);
        float sc = g[tid] * rs;
        sAux[tid] = sc;
        sAux[128 + tid] = be[tid] - mu * sc;
    }
    __syncthreads();
    float scR[8], shR[8];
#pragma unroll
    for (int e = 0; e < 8; ++e) {
        scR[e] = sAux[fb + e];
        shR[e] = sAux[128 + fb + e];
    }

    f32x4 acc[3];
#pragma unroll
    for (int ni = 0; ni < 3; ++ni) {
        int feat = ni * 16 + l16;
        float bv0 = (feat < 36) ? bl[feat] : 0.f;
        acc[ni][0] = bv0; acc[ni][1] = bv0; acc[ni][2] = bv0; acc[ni][3] = bv0;
    }

    f16x8 av[4];
    f16x8 bv[3];

    auto issueA = [&](int j) {
#pragma unroll
        for (int it = 0; it < 4; ++it) {
            int nl = t16 + it * 16;
            int n = m0 + nl;
            n = (n < N) ? n : (N - 1);
            long row = idx[n * 7 + j];
            av[it] = *(const f16x8*)&hprev[row * 128 + fb];
        }
    };
    auto issueB = [&](int j) {
#pragma unroll
        for (int it = 0; it < 3; ++it) {
            int ff = t16 + it * 16;
            bv[it] = *(const f16x8*)&WtF[(long)ff * 896 + j * 128 + fb];
        }
    };
    auto writeA = [&]() {
#pragma unroll
        for (int it = 0; it < 4; ++it) {
            int nl = t16 + it * 16;
            f16x8 hv = av[it];
            union { short sh8[8]; f16x8 v; } u;
#pragma unroll
            for (int e = 0; e < 8; ++e) {
                float v = (float)hv[e];
                u.sh8[e] = f2h(fmaxf(fmaf(v, scR[e], shR[e]), 0.f));
            }
            *(f16x8*)&sA[nl * 136 + fb] = u.v;
        }
    };
    auto writeB = [&]() {
#pragma unroll
        for (int it = 0; it < 3; ++it) {
            int ff = t16 + it * 16;
            *(f16x8*)&sB[ff * 136 + fb] = bv[it];
        }
    };

    issueB(0);
    issueA(0);

    for (int j = 0; j < 7; ++j) {
        __syncthreads();
        writeB();
        writeA();
        if (j < 6) {
            issueB(j + 1);
            issueA(j + 1);
        }
        __syncthreads();
#pragma unroll
        for (int k0 = 0; k0 < 128; k0 += 32) {
            f16x8 a = *(const f16x8*)&sA[(wave * 16 + l16) * 136 + k0 + quad * 8];
            f16x8 b[3];
#pragma unroll
            for (int ni = 0; ni < 3; ++ni)
                b[ni] = *(const f16x8*)&sB[(ni * 16 + l16) * 136 + k0 + quad * 8];
#pragma unroll
            for (int ni = 0; ni < 3; ++ni)
                acc[ni] = __builtin_amdgcn_mfma_f32_16x16x32_f16(a, b[ni], acc[ni], 0, 0, 0);
        }
    }

#pragma unroll
    for (int ni = 0; ni < 3; ++ni) {
        int feat = ni * 16 + l16;
        if (feat < 36) {
#pragma unroll
            for (int r = 0; r < 4; ++r) {
                int node = m0 + wave * 16 + quad * 4 + r;
                if (node < N) out[(long)node * 36 + feat] = acc[ni][r];
            }
        }
    }
}

// ---------------------------------------------------------------------------
extern "C" void kernel_launch(void* const* d_in, const int* in_sizes, int n_in,
                              void* d_out, int out_size, void* d_ws, size_t ws_size,
                              hipStream_t stream) {
    const float* x   = (const float*)d_in[0];
    const int*   idx = (const int*)d_in[1];
    const float* W0  = (const float*)d_in[2];
    const float* b0  = (const float*)d_in[3];
    const float* g0  = (const float*)d_in[4];
    const float* be0 = (const float*)d_in[5];
    const float* Wm  = (const float*)d_in[6];
    const float* bm  = (const float*)d_in[7];
    const float* gm  = (const float*)d_in[8];
    const float* bem = (const float*)d_in[9];
    const float* Wl  = (const float*)d_in[10];
    const float* bl  = (const float*)d_in[11];
    float* out = (float*)d_out;

    const int N = in_sizes[0] / 3;          // 40962
    const float invN = 1.0f / (float)N;

    char* ws = (char*)d_ws;
    size_t off = 0;
    auto alloc = [&](size_t bytes) -> void* {
        void* p = ws + off;
        off = (off + bytes + 255) & ~(size_t)255;
        return p;
    };
    short* WtM   = (short*)alloc(14UL * 128 * 896 * 2);
    short* WtF   = (short*)alloc(48UL * 896 * 2);
    float* stats = (float*)alloc(15UL * 256 * 4);
    short* hlinA = (short*)alloc((size_t)N * 128 * 2);
    short* hlinB = (short*)alloc((size_t)N * 128 * 2);

    {
        long total = 14L * 896 * 128 + 48L * 896 + 15L * 256;
        int blocks = (int)((total + 255) / 256);
        prep_kernel<<<blocks, 256, 0, stream>>>(Wm, Wl, WtM, WtF, stats);
    }

    layer0_kernel<<<1280, 256, 0, stream>>>(x, idx, W0, b0, hlinA, stats, N);

    const int nT = (N + 31) / 32;                       // 1281 node-tiles
    const int gblocks_mid = ((nT * 2 + 15) / 16) * 16;  // 2576 (16-block XCD chunks)
    short* hin = hlinA;
    short* hout = hlinB;
    const float* gPrev = g0;
    const float* bePrev = be0;
    for (int L = 0; L < 14; ++L) {
        gemm_mid_kernel<<<gblocks_mid, 256, 0, stream>>>(
            hin, idx, WtM + (size_t)L * 128 * 896, bm + L * 128,
            gPrev, bePrev, stats + L * 256,
            hout, stats + (L + 1) * 256, N, invN);
        gPrev = gm + L * 128;
        bePrev = bem + L * 128;
        short* t = hin; hin = hout; hout = t;
    }

    const int gblocks_fin = (N + 63) / 64;
    gemm_final_kernel<<<gblocks_fin, 256, 0, stream>>>(
        hin, idx, WtF, bl, gm + 13 * 128, bem + 13 * 128, stats + 14 * 256,
        out, N, invN);
}

// Round 12
// 598.703 us; speedup vs baseline: 1.2655x; 1.2655x over previous
//
#include <hip/hip_runtime.h>

typedef _Float16 f16x8 __attribute__((ext_vector_type(8)));
typedef float f32x4 __attribute__((ext_vector_type(4)));

#define EPS 1e-5f

__device__ __forceinline__ short f2h(float x) {
    _Float16 h = (_Float16)x;   // round-to-nearest-even v_cvt_f16_f32
    union { _Float16 h; short s; } u;
    u.h = h;
    return u.s;
}

// ---------------------------------------------------------------------------
// prep: transpose+convert Wm -> WtM[l][f][k] fp16, Wl -> WtF[f][k] fp16 (f padded
// to 48 with zeros), zero the stats buffers. Runs every call (ws is re-poisoned).
// ---------------------------------------------------------------------------
__global__ void prep_kernel(const float* __restrict__ Wm, const float* __restrict__ Wl,
                            short* __restrict__ WtM, short* __restrict__ WtF,
                            float* __restrict__ stats) {
    const long T1 = 14L * 896 * 128;
    const long T2 = 48L * 896;
    const long T3 = 15L * 256;
    long i = (long)blockIdx.x * blockDim.x + threadIdx.x;
    if (i < T1) {
        long l = i / (896 * 128);
        long r = i % (896 * 128);
        long k = r >> 7;
        long f = r & 127;
        WtM[l * 114688 + f * 896 + k] = f2h(Wm[i]);
    } else if (i < T1 + T2) {
        long j = i - T1;
        long f = j / 896;
        long k = j % 896;
        WtF[j] = (f < 36) ? f2h(Wl[k * 36 + f]) : (short)0;
    } else if (i < T1 + T2 + T3) {
        stats[i - T1 - T2] = 0.0f;
    }
}

// ---------------------------------------------------------------------------
// layer0: h[n,f] = b0[f] + sum_{k<21} x[idx[n,k/3], k%3] * W0[k,f]
// W in 21 registers; grid-stride (1280 blocks) with depth-1 register prefetch
// of the gathered x staging. fp32 math; fp16 output + exact fp32 stats.
// (R8 version verbatim.)
// ---------------------------------------------------------------------------
#define L0_NB 16
__global__ __launch_bounds__(256) void layer0_kernel(
        const float* __restrict__ x, const int* __restrict__ idx,
        const float* __restrict__ W0, const float* __restrict__ b0,
        short* __restrict__ hlin, float* __restrict__ stats, int N) {
    __shared__ float sX[L0_NB * 21];
    __shared__ float sStat[256];
    const int tid = threadIdx.x;
    const int f = tid & 127;
    const int half = tid >> 7;
    float wreg[21];
#pragma unroll
    for (int k = 0; k < 21; ++k) wreg[k] = W0[k * 128 + f];
    const float bf = b0[f];
    float s = 0.f, ss = 0.f;
    const int ntiles = (N + L0_NB - 1) / L0_NB;
    const int gs = gridDim.x;

    const int e0 = tid;                 // always < 336
    const int ni0 = e0 / 21, k0e = e0 - ni0 * 21;
    const int j0 = k0e / 3, c0 = k0e - j0 * 3;
    const int e1 = tid + 256;           // valid only for tid < 80
    const int ni1 = e1 / 21, k1e = e1 - ni1 * 21;
    const int j1 = k1e / 3, c1 = k1e - j1 * 3;

    auto issueX = [&](int t, float& a0, float& a1) {
        if (t >= ntiles) return;
        const int base = t * L0_NB;
        int n = base + ni0; if (n >= N) n = N - 1;
        a0 = x[(long)idx[n * 7 + j0] * 3 + c0];
        if (tid < 80) {
            int n2 = base + ni1; if (n2 >= N) n2 = N - 1;
            a1 = x[(long)idx[n2 * 7 + j1] * 3 + c1];
        }
    };

    float cx0 = 0.f, cx1 = 0.f, nx0 = 0.f, nx1 = 0.f;
    issueX(blockIdx.x, cx0, cx1);

    for (int t = blockIdx.x; t < ntiles; t += gs) {
        const int n0 = t * L0_NB;
        __syncthreads();                 // sX free (previous compute done)
        sX[e0] = cx0;                    // consume prefetch (vmcnt waits here)
        if (tid < 80) sX[e1] = cx1;
        issueX(t + gs, nx0, nx1);        // issue next tile BEFORE compute
        __syncthreads();
#pragma unroll
        for (int ni = 0; ni < 8; ++ni) {
            int node = n0 + half * 8 + ni;
            if (node >= N) break;        // per-thread, no barrier inside
            float acc = bf;
#pragma unroll
            for (int k = 0; k < 21; ++k)
                acc = fmaf(sX[(half * 8 + ni) * 21 + k], wreg[k], acc);
            hlin[(long)node * 128 + f] = f2h(acc);
            s += acc;
            ss += acc * acc;
        }
        cx0 = nx0; cx1 = nx1;            // plain register moves (no dyn index)
    }
    __syncthreads();
    if (half == 1) { sStat[f] = s; sStat[128 + f] = ss; }
    __syncthreads();
    if (half == 0) {
        atomicAdd(&stats[f], s + sStat[f]);
        atomicAdd(&stats[128 + f], ss + sStat[128 + f]);
    }
}

// ---------------------------------------------------------------------------
// gemm_mid (R10 structure + LDS idx hoist):
//   FEAT-SPLIT 64 nodes x 64 feats, depth-1 register prefetch of A+B, fp16
//   gather -> fp32 BN+ReLU -> f16 sA, XCD-pair swizzle. NEW: the 448 tile
//   indices are loaded to sIdx ONCE per block, so the per-phase gather chain
//   is ds_read(~120cy)->gather instead of idx-L2-load(~250cy)->gather —
//   shortens the only partially-hidden dependent chain by ~150-250cy/phase.
//   LDS 38,144B -> still 4 blocks/CU (4x38,144 = 152.6KB <= 160KiB).
// Block: 256 thr = 4 waves; wave = 32 nodes (wm) x 32 feats (wf); acc[2][2].
// bx: tile=((bx>>4)<<3)|(bx&7), fg=(bx>>3)&1.
// ---------------------------------------------------------------------------
__global__ __launch_bounds__(256, 4) void gemm_mid_kernel(
        const short* __restrict__ hprev, const int* __restrict__ idx,
        const short* __restrict__ Wt, const float* __restrict__ bvec,
        const float* __restrict__ g, const float* __restrict__ be,
        const float* __restrict__ statsIn,
        short* __restrict__ hlin, float* __restrict__ statsOut,
        int N, float invN) {
    __shared__ short sA[64 * 136];   // [node][k] for current j
    __shared__ short sB[64 * 136];   // [feat_local][k] for current j
    __shared__ float sAux[256];      // sc|sh during staging; stats scratch later
    __shared__ int   sIdx[448];      // 64 nodes x 7 neighbors

    const int bx = blockIdx.x;
    const int tile = ((bx >> 4) << 3) | (bx & 7);
    const int fg = (bx >> 3) & 1;   // feature group: feats [fg*64, fg*64+64)
    const int nT = (N + 63) >> 6;
    if (tile >= nT) return;          // pad blocks exit before any barrier

    const int tid = threadIdx.x;
    const int wave = tid >> 6;
    const int lane = tid & 63;
    const int quad = lane >> 4;
    const int l16 = lane & 15;
    const int wm = wave & 1;        // node half (32 nodes)
    const int wf = wave >> 1;       // feat half of the 64 (32 feats)
    const int m0 = tile * 64;
    const int f0 = fg * 64;
    const int t16 = tid >> 4;       // 0..15: staging row group
    const int fb = (tid & 15) * 8;  // fixed k-chunk for staging (input feats)

    if (tid < 128) {
        float mu = statsIn[tid] * invN;
        float var = statsIn[128 + tid] * invN - mu * mu;
        float rs = rsqrtf(var + EPS);
        float sc = g[tid] * rs;
        sAux[tid] = sc;
        sAux[128 + tid] = be[tid] - mu * sc;
    }
    // idx hoist: 448 ints, 2 per thread (tid, tid+256 for tid<192)
    {
        long mx = (long)N * 7 - 1;
        long g0i = (long)m0 * 7 + tid;
        sIdx[tid] = idx[g0i < mx ? g0i : mx];
        if (tid < 192) {
            long g1i = g0i + 256;
            sIdx[tid + 256] = idx[g1i < mx ? g1i : mx];
        }
    }
    __syncthreads();
    float scR[8], shR[8];
#pragma unroll
    for (int e = 0; e < 8; ++e) {
        scR[e] = sAux[fb + e];
        shR[e] = sAux[128 + fb + e];
    }

    f32x4 acc[2][2];
#pragma unroll
    for (int ni = 0; ni < 2; ++ni) {
        float bv0 = bvec[f0 + wf * 32 + ni * 16 + l16];
#pragma unroll
        for (int mi = 0; mi < 2; ++mi) {
            acc[mi][ni][0] = bv0; acc[mi][ni][1] = bv0; acc[mi][ni][2] = bv0; acc[mi][ni][3] = bv0;
        }
    }

    f16x8 av[4];    // A prefetch: 4 gathered fp16 row-chunks
    f16x8 bv[4];    // B prefetch: 4 chunks of 8 fp16

    auto issueA = [&](int j) {
#pragma unroll
        for (int it = 0; it < 4; ++it) {
            int nl = t16 + it * 16;
            long row = sIdx[nl * 7 + j];
            av[it] = *(const f16x8*)&hprev[row * 128 + fb];
        }
    };
    auto issueB = [&](int j) {
#pragma unroll
        for (int it = 0; it < 4; ++it) {
            int ff = f0 + t16 + it * 16;
            bv[it] = *(const f16x8*)&Wt[(long)ff * 896 + j * 128 + fb];
        }
    };
    auto writeA = [&]() {
#pragma unroll
        for (int it = 0; it < 4; ++it) {
            int nl = t16 + it * 16;
            f16x8 hv = av[it];
            union { short sh8[8]; f16x8 v; } u;
#pragma unroll
            for (int e = 0; e < 8; ++e) {
                float v = (float)hv[e];
                u.sh8[e] = f2h(fmaxf(fmaf(v, scR[e], shR[e]), 0.f));
            }
            *(f16x8*)&sA[nl * 136 + fb] = u.v;
        }
    };
    auto writeB = [&]() {
#pragma unroll
        for (int it = 0; it < 4; ++it) {
            int ffl = t16 + it * 16;
            *(f16x8*)&sB[ffl * 136 + fb] = bv[it];
        }
    };

    issueB(0);
    issueA(0);

    for (int j = 0; j < 7; ++j) {
        __syncthreads();            // sA/sB free (previous MFMA done)
        writeB();                   // implicit vmcnt waits at first use
        writeA();
        if (j < 6) {                // issue j+1 BEFORE compute of j
            issueB(j + 1);
            issueA(j + 1);
        }
        __syncthreads();
#pragma unroll
        for (int k0 = 0; k0 < 128; k0 += 32) {
            f16x8 a[2], b[2];
#pragma unroll
            for (int mi = 0; mi < 2; ++mi)
                a[mi] = *(const f16x8*)&sA[(wm * 32 + mi * 16 + l16) * 136 + k0 + quad * 8];
#pragma unroll
            for (int ni = 0; ni < 2; ++ni)
                b[ni] = *(const f16x8*)&sB[(wf * 32 + ni * 16 + l16) * 136 + k0 + quad * 8];
#pragma unroll
            for (int mi = 0; mi < 2; ++mi)
#pragma unroll
                for (int ni = 0; ni < 2; ++ni)
                    acc[mi][ni] = __builtin_amdgcn_mfma_f32_16x16x32_f16(a[mi], b[ni], acc[mi][ni], 0, 0, 0);
        }
    }

    // epilogue: store h fp16 (pre-BN), accumulate per-feature fp32 stats
    __syncthreads();
    if (tid < 128) sAux[tid] = 0.f;
    __syncthreads();
#pragma unroll
    for (int ni = 0; ni < 2; ++ni) {
        int lf = wf * 32 + ni * 16 + l16;     // local feat 0..63
        float s = 0.f, ss = 0.f;
#pragma unroll
        for (int mi = 0; mi < 2; ++mi) {
#pragma unroll
            for (int r = 0; r < 4; ++r) {
                int node = m0 + wm * 32 + mi * 16 + quad * 4 + r;
                float v = acc[mi][ni][r];
                if (node < N) {
                    hlin[(long)node * 128 + f0 + lf] = f2h(v);
                    s += v;
                    ss += v * v;
                }
            }
        }
        atomicAdd(&sAux[lf], s);
        atomicAdd(&sAux[64 + lf], ss);
    }
    __syncthreads();
    if (tid < 64) {
        atomicAdd(&statsOut[f0 + tid], sAux[tid]);
        atomicAdd(&statsOut[128 + f0 + tid], sAux[64 + tid]);
    }
}

// ---------------------------------------------------------------------------
// gemm_final (R8 structure + LDS idx hoist):
//   out[N,36] = gather7(relu(bn(hprev)))[N,896] @ Wl + bl
// WtF: [48][896] fp16 (feats 36..47 zero). Block: 64 nodes, wave = 16 nodes x 48 feats.
// ---------------------------------------------------------------------------
__global__ __launch_bounds__(256) void gemm_final_kernel(
        const short* __restrict__ hprev, const int* __restrict__ idx,
        const short* __restrict__ WtF, const float* __restrict__ bl,
        const float* __restrict__ g, const float* __restrict__ be,
        const float* __restrict__ statsIn,
        float* __restrict__ out, int N, float invN) {
    __shared__ short sA[64 * 136];
    __shared__ short sB[48 * 136];
    __shared__ float sAux[256];
    __shared__ int   sIdx[448];

    const int tid = threadIdx.x;
    const int wave = tid >> 6;
    const int lane = tid & 63;
    const int quad = lane >> 4;
    const int l16 = lane & 15;
    const int m0 = blockIdx.x * 64;
    const int t16 = tid >> 4;
    const int fb = (tid & 15) * 8;

    if (tid < 128) {
        float mu = statsIn[tid] * invN;
        float var = statsIn[128 + tid] * invN - mu * mu;
        float rs = rsqrtf(var + EPS);
        float sc = g[tid] * rs;
        sAux[tid] = sc;
        sAux[128 + tid] = be[tid] - mu * sc;
    }
    {
        long mx = (long)N * 7 - 1;
        long g0i = (long)m0 * 7 + tid;
        sIdx[tid] = idx[g0i < mx ? g0i : mx];
        if (tid < 192) {
            long g1i = g0i + 256;
            sIdx[tid + 256] = idx[g1i < mx ? g1i : mx];
        }
    }
    __syncthreads();
    float scR[8], shR[8];
#pragma unroll
    for (int e = 0; e < 8; ++e) {
        scR[e] = sAux[fb + e];
        shR[e] = sAux[128 + fb + e];
    }

    f32x4 acc[3];
#pragma unroll
    for (int ni = 0; ni < 3; ++ni) {
        int feat = ni * 16 + l16;
        float bv0 = (feat < 36) ? bl[feat] : 0.f;
        acc[ni][0] = bv0; acc[ni][1] = bv0; acc[ni][2] = bv0; acc[ni][3] = bv0;
    }

    f16x8 av[4];
    f16x8 bv[3];

    auto issueA = [&](int j) {
#pragma unroll
        for (int it = 0; it < 4; ++it) {
            int nl = t16 + it * 16;
            long row = sIdx[nl * 7 + j];
            av[it] = *(const f16x8*)&hprev[row * 128 + fb];
        }
    };
    auto issueB = [&](int j) {
#pragma unroll
        for (int it = 0; it < 3; ++it) {
            int ff = t16 + it * 16;
            bv[it] = *(const f16x8*)&WtF[(long)ff * 896 + j * 128 + fb];
        }
    };
    auto writeA = [&]() {
#pragma unroll
        for (int it = 0; it < 4; ++it) {
            int nl = t16 + it * 16;
            f16x8 hv = av[it];
            union { short sh8[8]; f16x8 v; } u;
#pragma unroll
            for (int e = 0; e < 8; ++e) {
                float v = (float)hv[e];
                u.sh8[e] = f2h(fmaxf(fmaf(v, scR[e], shR[e]), 0.f));
            }
            *(f16x8*)&sA[nl * 136 + fb] = u.v;
        }
    };
    auto writeB = [&]() {
#pragma unroll
        for (int it = 0; it < 3; ++it) {
            int ff = t16 + it * 16;
            *(f16x8*)&sB[ff * 136 + fb] = bv[it];
        }
    };

    issueB(0);
    issueA(0);

    for (int j = 0; j < 7; ++j) {
        __syncthreads();
        writeB();
        writeA();
        if (j < 6) {
            issueB(j + 1);
            issueA(j + 1);
        }
        __syncthreads();
#pragma unroll
        for (int k0 = 0; k0 < 128; k0 += 32) {
            f16x8 a = *(const f16x8*)&sA[(wave * 16 + l16) * 136 + k0 + quad * 8];
            f16x8 b[3];
#pragma unroll
            for (int ni = 0; ni < 3; ++ni)
                b[ni] = *(const f16x8*)&sB[(ni * 16 + l16) * 136 + k0 + quad * 8];
#pragma unroll
            for (int ni = 0; ni < 3; ++ni)
                acc[ni] = __builtin_amdgcn_mfma_f32_16x16x32_f16(a, b[ni], acc[ni], 0, 0, 0);
        }
    }

#pragma unroll
    for (int ni = 0; ni < 3; ++ni) {
        int feat = ni * 16 + l16;
        if (feat < 36) {
#pragma unroll
            for (int r = 0; r < 4; ++r) {
                int node = m0 + wave * 16 + quad * 4 + r;
                if (node < N) out[(long)node * 36 + feat] = acc[ni][r];
            }
        }
    }
}

// ---------------------------------------------------------------------------
extern "C" void kernel_launch(void* const* d_in, const int* in_sizes, int n_in,
                              void* d_out, int out_size, void* d_ws, size_t ws_size,
                              hipStream_t stream) {
    const float* x   = (const float*)d_in[0];
    const int*   idx = (const int*)d_in[1];
    const float* W0  = (const float*)d_in[2];
    const float* b0  = (const float*)d_in[3];
    const float* g0  = (const float*)d_in[4];
    const float* be0 = (const float*)d_in[5];
    const float* Wm  = (const float*)d_in[6];
    const float* bm  = (const float*)d_in[7];
    const float* gm  = (const float*)d_in[8];
    const float* bem = (const float*)d_in[9];
    const float* Wl  = (const float*)d_in[10];
    const float* bl  = (const float*)d_in[11];
    float* out = (float*)d_out;

    const int N = in_sizes[0] / 3;          // 40962
    const float invN = 1.0f / (float)N;

    char* ws = (char*)d_ws;
    size_t off = 0;
    auto alloc = [&](size_t bytes) -> void* {
        void* p = ws + off;
        off = (off + bytes + 255) & ~(size_t)255;
        return p;
    };
    short* WtM   = (short*)alloc(14UL * 128 * 896 * 2);
    short* WtF   = (short*)alloc(48UL * 896 * 2);
    float* stats = (float*)alloc(15UL * 256 * 4);
    short* hlinA = (short*)alloc((size_t)N * 128 * 2);
    short* hlinB = (short*)alloc((size_t)N * 128 * 2);

    {
        long total = 14L * 896 * 128 + 48L * 896 + 15L * 256;
        int blocks = (int)((total + 255) / 256);
        prep_kernel<<<blocks, 256, 0, stream>>>(Wm, Wl, WtM, WtF, stats);
    }

    layer0_kernel<<<1280, 256, 0, stream>>>(x, idx, W0, b0, hlinA, stats, N);

    const int nT = (N + 63) / 64;                       // 641 node-tiles
    const int gblocks_mid = ((nT * 2 + 15) / 16) * 16;  // 1296 (16-block XCD chunks)
    short* hin = hlinA;
    short* hout = hlinB;
    const float* gPrev = g0;
    const float* bePrev = be0;
    for (int L = 0; L < 14; ++L) {
        gemm_mid_kernel<<<gblocks_mid, 256, 0, stream>>>(
            hin, idx, WtM + (size_t)L * 128 * 896, bm + L * 128,
            gPrev, bePrev, stats + L * 256,
            hout, stats + (L + 1) * 256, N, invN);
        gPrev = gm + L * 128;
        bePrev = bem + L * 128;
        short* t = hin; hin = hout; hout = t;
    }

    const int gblocks_fin = (N + 63) / 64;
    gemm_final_kernel<<<gblocks_fin, 256, 0, stream>>>(
        hin, idx, WtF, bl, gm + 13 * 128, bem + 13 * 128, stats + 14 * 256,
        out, N, invN);
}

// Round 13
// 584.672 us; speedup vs baseline: 1.2959x; 1.0240x over previous
//
#include <hip/hip_runtime.h>

typedef _Float16 f16x8 __attribute__((ext_vector_type(8)));
typedef float f32x4 __attribute__((ext_vector_type(4)));

#define EPS 1e-5f

__device__ __forceinline__ short f2h(float x) {
    _Float16 h = (_Float16)x;   // round-to-nearest-even v_cvt_f16_f32
    union { _Float16 h; short s; } u;
    u.h = h;
    return u.s;
}

// ---------------------------------------------------------------------------
// prep: transpose+convert Wm -> WtM[l][f][k] fp16, Wl -> WtF[f][k] fp16 (f padded
// to 48 with zeros), zero the stats buffers. Runs every call (ws is re-poisoned).
// ---------------------------------------------------------------------------
__global__ void prep_kernel(const float* __restrict__ Wm, const float* __restrict__ Wl,
                            short* __restrict__ WtM, short* __restrict__ WtF,
                            float* __restrict__ stats) {
    const long T1 = 14L * 896 * 128;
    const long T2 = 48L * 896;
    const long T3 = 15L * 256;
    long i = (long)blockIdx.x * blockDim.x + threadIdx.x;
    if (i < T1) {
        long l = i / (896 * 128);
        long r = i % (896 * 128);
        long k = r >> 7;
        long f = r & 127;
        WtM[l * 114688 + f * 896 + k] = f2h(Wm[i]);
    } else if (i < T1 + T2) {
        long j = i - T1;
        long f = j / 896;
        long k = j % 896;
        WtF[j] = (f < 36) ? f2h(Wl[k * 36 + f]) : (short)0;
    } else if (i < T1 + T2 + T3) {
        stats[i - T1 - T2] = 0.0f;
    }
}

// ---------------------------------------------------------------------------
// layer0: h[n,f] = b0[f] + sum_{k<21} x[idx[n,k/3], k%3] * W0[k,f]
// W in 21 registers; grid-stride (1280 blocks) with depth-1 register prefetch
// of the gathered x staging. fp32 math; fp16 output + exact fp32 stats.
// ---------------------------------------------------------------------------
#define L0_NB 16
__global__ __launch_bounds__(256) void layer0_kernel(
        const float* __restrict__ x, const int* __restrict__ idx,
        const float* __restrict__ W0, const float* __restrict__ b0,
        short* __restrict__ hlin, float* __restrict__ stats, int N) {
    __shared__ float sX[L0_NB * 21];
    __shared__ float sStat[256];
    const int tid = threadIdx.x;
    const int f = tid & 127;
    const int half = tid >> 7;
    float wreg[21];
#pragma unroll
    for (int k = 0; k < 21; ++k) wreg[k] = W0[k * 128 + f];
    const float bf = b0[f];
    float s = 0.f, ss = 0.f;
    const int ntiles = (N + L0_NB - 1) / L0_NB;
    const int gs = gridDim.x;

    const int e0 = tid;                 // always < 336
    const int ni0 = e0 / 21, k0e = e0 - ni0 * 21;
    const int j0 = k0e / 3, c0 = k0e - j0 * 3;
    const int e1 = tid + 256;           // valid only for tid < 80
    const int ni1 = e1 / 21, k1e = e1 - ni1 * 21;
    const int j1 = k1e / 3, c1 = k1e - j1 * 3;

    auto issueX = [&](int t, float& a0, float& a1) {
        if (t >= ntiles) return;
        const int base = t * L0_NB;
        int n = base + ni0; if (n >= N) n = N - 1;
        a0 = x[(long)idx[n * 7 + j0] * 3 + c0];
        if (tid < 80) {
            int n2 = base + ni1; if (n2 >= N) n2 = N - 1;
            a1 = x[(long)idx[n2 * 7 + j1] * 3 + c1];
        }
    };

    float cx0 = 0.f, cx1 = 0.f, nx0 = 0.f, nx1 = 0.f;
    issueX(blockIdx.x, cx0, cx1);

    for (int t = blockIdx.x; t < ntiles; t += gs) {
        const int n0 = t * L0_NB;
        __syncthreads();                 // sX free (previous compute done)
        sX[e0] = cx0;                    // consume prefetch (vmcnt waits here)
        if (tid < 80) sX[e1] = cx1;
        issueX(t + gs, nx0, nx1);        // issue next tile BEFORE compute
        __syncthreads();
#pragma unroll
        for (int ni = 0; ni < 8; ++ni) {
            int node = n0 + half * 8 + ni;
            if (node >= N) break;        // per-thread, no barrier inside
            float acc = bf;
#pragma unroll
            for (int k = 0; k < 21; ++k)
                acc = fmaf(sX[(half * 8 + ni) * 21 + k], wreg[k], acc);
            hlin[(long)node * 128 + f] = f2h(acc);
            s += acc;
            ss += acc * acc;
        }
        cx0 = nx0; cx1 = nx1;            // plain register moves (no dyn index)
    }
    __syncthreads();
    if (half == 1) { sStat[f] = s; sStat[128 + f] = ss; }
    __syncthreads();
    if (half == 0) {
        atomicAdd(&stats[f], s + sStat[f]);
        atomicAdd(&stats[128 + f], ss + sStat[128 + f]);
    }
}

// ---------------------------------------------------------------------------
// gemm_mid (BN-fused, software-pipelined, FEAT-SPLIT 64 nodes x 64 feats,
// XCD-PAIR SWIZZLE) — best verified configuration (R10, 594us total):
//   fp16 gather -> fp32 BN+ReLU -> f16 sA; depth-1 register prefetch of A+B
//   issued before the MFMA phase; 4 blocks/CU. Block mapping puts the two
//   feat-group blocks of the SAME 64-node tile on the SAME XCD (bx and bx+8
//   share bx%8 under round-robin dispatch) so the second block's 448-row
//   A-gather (114KB, identical rows) partially hits the XCD-local L2.
//   bx in [0,1296): tile=((bx>>4)<<3)|(bx&7), fg=(bx>>3)&1.
// Block: 256 thr = 4 waves; wave = 32 nodes (wm) x 32 feats (wf); acc[2][2].
// ---------------------------------------------------------------------------
__global__ __launch_bounds__(256, 4) void gemm_mid_kernel(
        const short* __restrict__ hprev, const int* __restrict__ idx,
        const short* __restrict__ Wt, const float* __restrict__ bvec,
        const float* __restrict__ g, const float* __restrict__ be,
        const float* __restrict__ statsIn,
        short* __restrict__ hlin, float* __restrict__ statsOut,
        int N, float invN) {
    __shared__ short sA[64 * 136];   // [node][k] for current j
    __shared__ short sB[64 * 136];   // [feat_local][k] for current j
    __shared__ float sAux[256];      // sc|sh during staging; stats scratch later

    const int bx = blockIdx.x;
    const int tile = ((bx >> 4) << 3) | (bx & 7);
    const int fg = (bx >> 3) & 1;   // feature group: feats [fg*64, fg*64+64)
    const int nT = (N + 63) >> 6;
    if (tile >= nT) return;          // pad blocks exit before any barrier

    const int tid = threadIdx.x;
    const int wave = tid >> 6;
    const int lane = tid & 63;
    const int quad = lane >> 4;
    const int l16 = lane & 15;
    const int wm = wave & 1;        // node half (32 nodes)
    const int wf = wave >> 1;       // feat half of the 64 (32 feats)
    const int m0 = tile * 64;
    const int f0 = fg * 64;
    const int t16 = tid >> 4;       // 0..15: staging row group
    const int fb = (tid & 15) * 8;  // fixed k-chunk for staging (input feats)

    if (tid < 128) {
        float mu = statsIn[tid] * invN;
        float var = statsIn[128 + tid] * invN - mu * mu;
        float rs = rsqrtf(var + EPS);
        float sc = g[tid] * rs;
        sAux[tid] = sc;
        sAux[128 + tid] = be[tid] - mu * sc;
    }
    __syncthreads();
    float scR[8], shR[8];
#pragma unroll
    for (int e = 0; e < 8; ++e) {
        scR[e] = sAux[fb + e];
        shR[e] = sAux[128 + fb + e];
    }

    f32x4 acc[2][2];
#pragma unroll
    for (int ni = 0; ni < 2; ++ni) {
        float bv0 = bvec[f0 + wf * 32 + ni * 16 + l16];
#pragma unroll
        for (int mi = 0; mi < 2; ++mi) {
            acc[mi][ni][0] = bv0; acc[mi][ni][1] = bv0; acc[mi][ni][2] = bv0; acc[mi][ni][3] = bv0;
        }
    }

    f16x8 av[4];    // A prefetch: 4 gathered fp16 row-chunks
    f16x8 bv[4];    // B prefetch: 4 chunks of 8 fp16

    auto issueA = [&](int j) {
#pragma unroll
        for (int it = 0; it < 4; ++it) {
            int nl = t16 + it * 16;
            int n = m0 + nl;
            n = (n < N) ? n : (N - 1);
            long row = idx[n * 7 + j];
            av[it] = *(const f16x8*)&hprev[row * 128 + fb];
        }
    };
    auto issueB = [&](int j) {
#pragma unroll
        for (int it = 0; it < 4; ++it) {
            int ff = f0 + t16 + it * 16;
            bv[it] = *(const f16x8*)&Wt[(long)ff * 896 + j * 128 + fb];
        }
    };
    auto writeA = [&]() {
#pragma unroll
        for (int it = 0; it < 4; ++it) {
            int nl = t16 + it * 16;
            f16x8 hv = av[it];
            union { short sh8[8]; f16x8 v; } u;
#pragma unroll
            for (int e = 0; e < 8; ++e) {
                float v = (float)hv[e];
                u.sh8[e] = f2h(fmaxf(fmaf(v, scR[e], shR[e]), 0.f));
            }
            *(f16x8*)&sA[nl * 136 + fb] = u.v;
        }
    };
    auto writeB = [&]() {
#pragma unroll
        for (int it = 0; it < 4; ++it) {
            int ffl = t16 + it * 16;
            *(f16x8*)&sB[ffl * 136 + fb] = bv[it];
        }
    };

    issueB(0);
    issueA(0);

    for (int j = 0; j < 7; ++j) {
        __syncthreads();            // sA/sB free (previous MFMA done)
        writeB();                   // implicit vmcnt waits at first use
        writeA();
        if (j < 6) {                // issue j+1 BEFORE compute of j
            issueB(j + 1);
            issueA(j + 1);
        }
        __syncthreads();
#pragma unroll
        for (int k0 = 0; k0 < 128; k0 += 32) {
            f16x8 a[2], b[2];
#pragma unroll
            for (int mi = 0; mi < 2; ++mi)
                a[mi] = *(const f16x8*)&sA[(wm * 32 + mi * 16 + l16) * 136 + k0 + quad * 8];
#pragma unroll
            for (int ni = 0; ni < 2; ++ni)
                b[ni] = *(const f16x8*)&sB[(wf * 32 + ni * 16 + l16) * 136 + k0 + quad * 8];
#pragma unroll
            for (int mi = 0; mi < 2; ++mi)
#pragma unroll
                for (int ni = 0; ni < 2; ++ni)
                    acc[mi][ni] = __builtin_amdgcn_mfma_f32_16x16x32_f16(a[mi], b[ni], acc[mi][ni], 0, 0, 0);
        }
    }

    // epilogue: store h fp16 (pre-BN), accumulate per-feature fp32 stats
    __syncthreads();
    if (tid < 128) sAux[tid] = 0.f;
    __syncthreads();
#pragma unroll
    for (int ni = 0; ni < 2; ++ni) {
        int lf = wf * 32 + ni * 16 + l16;     // local feat 0..63
        float s = 0.f, ss = 0.f;
#pragma unroll
        for (int mi = 0; mi < 2; ++mi) {
#pragma unroll
            for (int r = 0; r < 4; ++r) {
                int node = m0 + wm * 32 + mi * 16 + quad * 4 + r;
                float v = acc[mi][ni][r];
                if (node < N) {
                    hlin[(long)node * 128 + f0 + lf] = f2h(v);
                    s += v;
                    ss += v * v;
                }
            }
        }
        atomicAdd(&sAux[lf], s);
        atomicAdd(&sAux[64 + lf], ss);
    }
    __syncthreads();
    if (tid < 64) {
        atomicAdd(&statsOut[f0 + tid], sAux[tid]);
        atomicAdd(&statsOut[128 + f0 + tid], sAux[64 + tid]);
    }
}

// ---------------------------------------------------------------------------
// gemm_final (BN-fused, software-pipelined, fp16 h gather):
//   out[N,36] = gather7(relu(bn(hprev)))[N,896] @ Wl + bl
// WtF: [48][896] fp16 (feats 36..47 zero). Block: 64 nodes, wave = 16 nodes x 48 feats.
// ---------------------------------------------------------------------------
__global__ __launch_bounds__(256) void gemm_final_kernel(
        const short* __restrict__ hprev, const int* __restrict__ idx,
        const short* __restrict__ WtF, const float* __restrict__ bl,
        const float* __restrict__ g, const float* __restrict__ be,
        const float* __restrict__ statsIn,
        float* __restrict__ out, int N, float invN) {
    __shared__ short sA[64 * 136];
    __shared__ short sB[48 * 136];
    __shared__ float sAux[256];

    const int tid = threadIdx.x;
    const int wave = tid >> 6;
    const int lane = tid & 63;
    const int quad = lane >> 4;
    const int l16 = lane & 15;
    const int m0 = blockIdx.x * 64;
    const int t16 = tid >> 4;
    const int fb = (tid & 15) * 8;

    if (tid < 128) {
        float mu = statsIn[tid] * invN;
        float var = statsIn[128 + tid] * invN - mu * mu;
        float rs = rsqrtf(var + EPS);
        float sc = g[tid] * rs;
        sAux[tid] = sc;
        sAux[128 + tid] = be[tid] - mu * sc;
    }
    __syncthreads();
    float scR[8], shR[8];
#pragma unroll
    for (int e = 0; e < 8; ++e) {
        scR[e] = sAux[fb + e];
        shR[e] = sAux[128 + fb + e];
    }

    f32x4 acc[3];
#pragma unroll
    for (int ni = 0; ni < 3; ++ni) {
        int feat = ni * 16 + l16;
        float bv0 = (feat < 36) ? bl[feat] : 0.f;
        acc[ni][0] = bv0; acc[ni][1] = bv0; acc[ni][2] = bv0; acc[ni][3] = bv0;
    }

    f16x8 av[4];
    f16x8 bv[3];

    auto issueA = [&](int j) {
#pragma unroll
        for (int it = 0; it < 4; ++it) {
            int nl = t16 + it * 16;
            int n = m0 + nl;
            n = (n < N) ? n : (N - 1);
            long row = idx[n * 7 + j];
            av[it] = *(const f16x8*)&hprev[row * 128 + fb];
        }
    };
    auto issueB = [&](int j) {
#pragma unroll
        for (int it = 0; it < 3; ++it) {
            int ff = t16 + it * 16;
            bv[it] = *(const f16x8*)&WtF[(long)ff * 896 + j * 128 + fb];
        }
    };
    auto writeA = [&]() {
#pragma unroll
        for (int it = 0; it < 4; ++it) {
            int nl = t16 + it * 16;
            f16x8 hv = av[it];
            union { short sh8[8]; f16x8 v; } u;
#pragma unroll
            for (int e = 0; e < 8; ++e) {
                float v = (float)hv[e];
                u.sh8[e] = f2h(fmaxf(fmaf(v, scR[e], shR[e]), 0.f));
            }
            *(f16x8*)&sA[nl * 136 + fb] = u.v;
        }
    };
    auto writeB = [&]() {
#pragma unroll
        for (int it = 0; it < 3; ++it) {
            int ff = t16 + it * 16;
            *(f16x8*)&sB[ff * 136 + fb] = bv[it];
        }
    };

    issueB(0);
    issueA(0);

    for (int j = 0; j < 7; ++j) {
        __syncthreads();
        writeB();
        writeA();
        if (j < 6) {
            issueB(j + 1);
            issueA(j + 1);
        }
        __syncthreads();
#pragma unroll
        for (int k0 = 0; k0 < 128; k0 += 32) {
            f16x8 a = *(const f16x8*)&sA[(wave * 16 + l16) * 136 + k0 + quad * 8];
            f16x8 b[3];
#pragma unroll
            for (int ni = 0; ni < 3; ++ni)
                b[ni] = *(const f16x8*)&sB[(ni * 16 + l16) * 136 + k0 + quad * 8];
#pragma unroll
            for (int ni = 0; ni < 3; ++ni)
                acc[ni] = __builtin_amdgcn_mfma_f32_16x16x32_f16(a, b[ni], acc[ni], 0, 0, 0);
        }
    }

#pragma unroll
    for (int ni = 0; ni < 3; ++ni) {
        int feat = ni * 16 + l16;
        if (feat < 36) {
#pragma unroll
            for (int r = 0; r < 4; ++r) {
                int node = m0 + wave * 16 + quad * 4 + r;
                if (node < N) out[(long)node * 36 + feat] = acc[ni][r];
            }
        }
    }
}

// ---------------------------------------------------------------------------
extern "C" void kernel_launch(void* const* d_in, const int* in_sizes, int n_in,
                              void* d_out, int out_size, void* d_ws, size_t ws_size,
                              hipStream_t stream) {
    const float* x   = (const float*)d_in[0];
    const int*   idx = (const int*)d_in[1];
    const float* W0  = (const float*)d_in[2];
    const float* b0  = (const float*)d_in[3];
    const float* g0  = (const float*)d_in[4];
    const float* be0 = (const float*)d_in[5];
    const float* Wm  = (const float*)d_in[6];
    const float* bm  = (const float*)d_in[7];
    const float* gm  = (const float*)d_in[8];
    const float* bem = (const float*)d_in[9];
    const float* Wl  = (const float*)d_in[10];
    const float* bl  = (const float*)d_in[11];
    float* out = (float*)d_out;

    const int N = in_sizes[0] / 3;          // 40962
    const float invN = 1.0f / (float)N;

    char* ws = (char*)d_ws;
    size_t off = 0;
    auto alloc = [&](size_t bytes) -> void* {
        void* p = ws + off;
        off = (off + bytes + 255) & ~(size_t)255;
        return p;
    };
    short* WtM   = (short*)alloc(14UL * 128 * 896 * 2);
    short* WtF   = (short*)alloc(48UL * 896 * 2);
    float* stats = (float*)alloc(15UL * 256 * 4);
    short* hlinA = (short*)alloc((size_t)N * 128 * 2);
    short* hlinB = (short*)alloc((size_t)N * 128 * 2);

    {
        long total = 14L * 896 * 128 + 48L * 896 + 15L * 256;
        int blocks = (int)((total + 255) / 256);
        prep_kernel<<<blocks, 256, 0, stream>>>(Wm, Wl, WtM, WtF, stats);
    }

    layer0_kernel<<<1280, 256, 0, stream>>>(x, idx, W0, b0, hlinA, stats, N);

    const int nT = (N + 63) / 64;                       // 641 node-tiles
    const int gblocks_mid = ((nT * 2 + 15) / 16) * 16;  // 1296 (16-block XCD chunks)
    short* hin = hlinA;
    short* hout = hlinB;
    const float* gPrev = g0;
    const float* bePrev = be0;
    for (int L = 0; L < 14; ++L) {
        gemm_mid_kernel<<<gblocks_mid, 256, 0, stream>>>(
            hin, idx, WtM + (size_t)L * 128 * 896, bm + L * 128,
            gPrev, bePrev, stats + L * 256,
            hout, stats + (L + 1) * 256, N, invN);
        gPrev = gm + L * 128;
        bePrev = bem + L * 128;
        short* t = hin; hin = hout; hout = t;
    }

    const int gblocks_fin = (N + 63) / 64;
    gemm_final_kernel<<<gblocks_fin, 256, 0, stream>>>(
        hin, idx, WtF, bl, gm + 13 * 128, bem + 13 * 128, stats + 14 * 256,
        out, N, invN);
}